// Round 1
// baseline (228.531 us; speedup 1.0000x reference)
//
#include <hip/hip_runtime.h>
#include <math.h>

// CTC forward (keras ctc_batch_cost semantics), B=1024 T=256 C=128 L=64.
// One block per batch element; 128 threads; thread s owns extended state s
// (thread 127 additionally owns state 128). y_pred staged in 8-row chunks
// via float4 register-prefetched loads; alpha double-buffered in LDS with
// one barrier per timestep.

#define Bn 1024
#define Tn 256
#define Cn 128
#define Ln 64
#define Sn 129          // 2L+1
#define BLANK 127       // C-1
#define NEGV (-1e30f)
#define EPSV (1e-7f)
#define CHUNK 8         // timesteps staged per iteration (8*128*4B = 4KB)

__global__ __launch_bounds__(128)
void ctc_fwd_kernel(const int* __restrict__ y_true,
                    const float* __restrict__ y_pred,
                    float* __restrict__ out) {
    const int b   = blockIdx.x;
    const int tid = threadIdx.x;

    __shared__ __align__(16) float prob[2][CHUNK * Cn];   // 8 KB
    __shared__ float alpha[2][Sn + 3];                    // states at [s+2]; [0..1] = NEG pad

    if (tid < 2) { alpha[0][tid] = NEGV; alpha[1][tid] = NEGV; }

    // Extended-label class + skip-allowed flag for this thread's state.
    const int* lab = y_true + b * Ln;
    int  cls;
    bool canskip;
    if (tid & 1) {
        const int li = tid >> 1;           // label index, 0..63
        const int lv = lab[li];
        cls = lv;
        canskip = (li == 0) ? true : (lv != lab[li - 1]);
    } else {
        cls = BLANK;
        canskip = false;
    }

    const float4* src = (const float4*)(y_pred + (size_t)b * (Tn * Cn));

    // Prefetch chunk 0 (rows 0..7) into registers.
    float4 p0 = src[tid];
    float4 p1 = src[tid + 128];

    int ab = 0;  // which alpha buffer holds "current" alpha
    for (int c = 0; c < Tn / CHUNK; ++c) {
        const int pbuf = c & 1;
        ((float4*)prob[pbuf])[tid]       = p0;
        ((float4*)prob[pbuf])[tid + 128] = p1;
        if (c + 1 < Tn / CHUNK) {
            const float4* s2 = src + (c + 1) * (CHUNK * Cn / 4);
            p0 = s2[tid];
            p1 = s2[tid + 128];
        }
        __syncthreads();  // prob[pbuf] visible to all

        const float* pr = prob[pbuf];
        #pragma unroll
        for (int tt = 0; tt < CHUNK; ++tt) {
            if (c == 0 && tt == 0) {
                // t = 0 init: only states 0 and 1 reachable.
                float* cur = alpha[ab];
                float v = NEGV;
                if (tid == 0)      v = __logf(pr[BLANK] + EPSV);
                else if (tid == 1) v = __logf(pr[cls]   + EPSV);
                cur[tid + 2] = v;
                if (tid == 127) cur[128 + 2] = NEGV;
                __syncthreads();
                continue;
            }
            const float* cur = alpha[ab];
            float*       nxt = alpha[ab ^ 1];
            const float* row = pr + tt * Cn;

            const float lp = __logf(row[cls] + EPSV);
            const float a0 = cur[tid + 2];          // alpha[s]
            const float a1 = cur[tid + 1];          // alpha[s-1]
            const float a2 = canskip ? cur[tid] : NEGV;  // alpha[s-2]
            const float m  = fmaxf(a0, fmaxf(a1, a2));
            const float r  = m + __logf(__expf(a0 - m) + __expf(a1 - m) + __expf(a2 - m)) + lp;

            float r128 = 0.0f;
            if (tid == 127) {  // state 128: blank, no skip
                const float b0 = cur[128 + 2];
                const float b1 = cur[127 + 2];
                const float lpb = __logf(row[BLANK] + EPSV);
                const float mm = fmaxf(b0, b1);
                r128 = mm + __logf(__expf(b0 - mm) + __expf(b1 - mm)) + lpb;
            }

            nxt[tid + 2] = r;
            if (tid == 127) nxt[128 + 2] = r128;
            ab ^= 1;
            __syncthreads();  // writes visible before next step's reads
        }
    }

    if (tid == 127) {
        const float* fin = alpha[ab];
        const float x = fin[128 + 2];   // end on last blank
        const float y = fin[127 + 2];   // or last label
        const float m = fmaxf(x, y);
        out[b] = -(m + __logf(__expf(x - m) + __expf(y - m)));
    }
}

extern "C" void kernel_launch(void* const* d_in, const int* in_sizes, int n_in,
                              void* d_out, int out_size, void* d_ws, size_t ws_size,
                              hipStream_t stream) {
    const int*   y_true = (const int*)d_in[0];
    const float* y_pred = (const float*)d_in[1];
    float*       out    = (float*)d_out;
    hipLaunchKernelGGL(ctc_fwd_kernel, dim3(Bn), dim3(128), 0, stream,
                       y_true, y_pred, out);
}

// Round 2
// 197.641 us; speedup vs baseline: 1.1563x; 1.1563x over previous
//
#include <hip/hip_runtime.h>
#include <math.h>

// CTC forward, keras ctc_batch_cost semantics. B=1024 T=256 C=128 L=64, S=129.
// One wave64 per batch element. Lane i owns extended states 2i+1 (label l_i)
// and 2i+2 (blank); alpha[0] (leading blank) is replicated on all lanes since
// its update is a pure add. Cross-lane dependency is only "lane i-1's previous
// alphas" -> two ds_bpermute per timestep, no barriers, no LDS staging.
// Entire recurrence runs in log2 space so v_exp_f32/v_log_f32 are native.
// Probabilities are gathered directly from global (L2/L3-resident), software-
// pipelined one 8-step group ahead; log2 conversion happens off the critical
// chain at group boundaries.

#define Bn 1024
#define Tn 256
#define Cn 128
#define Ln 64
#define BLANK 127
#define NEG2 (-1.0e30f)
#define EPSV (1e-7f)
#define U 8
#define NG (Tn / U)

#if __has_builtin(__builtin_amdgcn_exp2f)
#define EXP2(x) __builtin_amdgcn_exp2f(x)
#else
#define EXP2(x) exp2f(x)
#endif
#if __has_builtin(__builtin_amdgcn_logf)
#define LOG2(x) __builtin_amdgcn_logf(x)   // v_log_f32 = log2
#else
#define LOG2(x) log2f(x)
#endif

__global__ __launch_bounds__(64)
void ctc_wave_kernel(const int* __restrict__ y_true,
                     const float* __restrict__ y_pred,
                     float* __restrict__ out) {
    const int b = blockIdx.x;
    const int i = threadIdx.x;               // lane 0..63

    const int* lab = y_true + b * Ln;
    const int  li   = lab[i];
    const int  lim1 = (i == 0) ? -1 : lab[i - 1];
    const bool skip = (li != lim1);          // for i==0 the skip source is NEG anyway

    const float* base   = y_pred + (size_t)b * (Tn * Cn);
    const float* pl_ptr = base + li;         // this lane's label column
    const float* pb_ptr = base + BLANK;      // blank column (wave-uniform)

    const int baddr = ((i - 1) & 63) << 2;   // bpermute byte address: lane i-1

    float lpl[2][U], lpb[2][U];
    {   // prime group 0
        float rl[U], rb[U];
        #pragma unroll
        for (int j = 0; j < U; ++j) {
            rl[j] = pl_ptr[j * Cn];
            rb[j] = pb_ptr[j * Cn];
        }
        #pragma unroll
        for (int j = 0; j < U; ++j) {
            lpl[0][j] = LOG2(rl[j] + EPSV);
            lpb[0][j] = LOG2(rb[j] + EPSV);
        }
    }

    float A0 = NEG2, Aod = NEG2, Aev = NEG2;  // alpha[0], alpha[2i+1], alpha[2i+2]

    for (int g = 0; g < NG; ++g) {
        const int cur = g & 1, nxt = cur ^ 1;
        float rl[U], rb[U];
        if (g + 1 < NG) {                    // issue next group's loads early
            const float* pl2 = pl_ptr + (size_t)(g + 1) * U * Cn;
            const float* pb2 = pb_ptr + (size_t)(g + 1) * U * Cn;
            #pragma unroll
            for (int j = 0; j < U; ++j) {
                rl[j] = pl2[j * Cn];
                rb[j] = pb2[j * Cn];
            }
        }
        #pragma unroll
        for (int j = 0; j < U; ++j) {
            const float lb = lpb[cur][j];
            const float ll = lpl[cur][j];
            if (g == 0 && j == 0) {
                // t = 0 init: alpha[0] = lp2(blank), alpha[1] = lp2(l_0)
                A0  = lb;
                Aod = (i == 0) ? ll : NEG2;
                Aev = NEG2;
                continue;
            }
            // previous alphas from lane i-1
            const float odL_raw = __int_as_float(
                __builtin_amdgcn_ds_bpermute(baddr, __float_as_int(Aod)));
            const float evL_raw = __int_as_float(
                __builtin_amdgcn_ds_bpermute(baddr, __float_as_int(Aev)));
            const float evL = (i == 0) ? A0   : evL_raw;   // alpha[2i]
            const float odL = (i == 0) ? NEG2 : odL_raw;   // alpha[2i-1]

            // even state 2i+2 (blank, no skip): purely lane-local -> overlaps shfl
            const float m2  = fmaxf(Aev, Aod);
            const float d2  = fminf(Aev, Aod) - m2;
            const float nev = m2 + LOG2(1.0f + EXP2(d2)) + lb;

            // odd state 2i+1 (label): 3-way LSE with optional skip
            const float c3  = skip ? odL : NEG2;
            const float m3  = fmaxf(fmaxf(Aod, evL), c3);
            const float s3  = EXP2(Aod - m3) + EXP2(evL - m3) + EXP2(c3 - m3);
            const float nod = m3 + LOG2(s3) + ll;

            A0 += lb;
            Aod = nod;
            Aev = nev;
        }
        if (g + 1 < NG) {                    // off-chain log2 conversion
            #pragma unroll
            for (int j = 0; j < U; ++j) {
                lpl[nxt][j] = LOG2(rl[j] + EPSV);
                lpb[nxt][j] = LOG2(rb[j] + EPSV);
            }
        }
    }

    if (i == 63) {
        // alpha[128] = Aev, alpha[127] = Aod
        const float m = fmaxf(Aev, Aod);
        const float d = fminf(Aev, Aod) - m;
        const float ll2 = m + LOG2(1.0f + EXP2(d));
        out[b] = -(ll2 * 0.69314718055994530942f);  // back to natural log
    }
}

extern "C" void kernel_launch(void* const* d_in, const int* in_sizes, int n_in,
                              void* d_out, int out_size, void* d_ws, size_t ws_size,
                              hipStream_t stream) {
    const int*   y_true = (const int*)d_in[0];
    const float* y_pred = (const float*)d_in[1];
    float*       out    = (float*)d_out;
    hipLaunchKernelGGL(ctc_wave_kernel, dim3(Bn), dim3(64), 0, stream,
                       y_true, y_pred, out);
}

// Round 3
// 193.835 us; speedup vs baseline: 1.1790x; 1.0196x over previous
//
#include <hip/hip_runtime.h>
#include <math.h>

// CTC forward (keras ctc_batch_cost), B=1024 T=256 C=128 L=64, S=129.
// One wave64 per batch element; lane i owns states 2i+1 (label) and 2i+2
// (blank); alpha[0] replicated on all lanes. Recurrence runs in the
// PROBABILITY domain (exact semiring): a'[s] = (a[s]+a[s-1]+a[s-2])*q,
// q = (p+eps)*128. The x128 bias keeps magnitudes near 1; a wave-uniform
// renorm every 8 steps (DPP max-reduce, exponent stripped into Esum) kills
// under/overflow. Cross-lane shift-by-1 via v_mov_b32_dpp wave_shr:1 --
// VALU latency, no LDS, no barriers; lane 0 gets 0 = additive identity.
// Probabilities gathered from global with ping-pong raw buffers (static
// indexing only -- no scratch), prefetch depth ~2 groups.

#define Bn 1024
#define Tn 256
#define Cn 128
#define Ln 64
#define BLANK 127
#define U 8
#define NG (Tn / U)
#define EPS128 (1e-7f * 128.0f)
#define LN2 0.69314718055994530942f

template <int CTRL>
__device__ __forceinline__ float dpp_mov(float x) {
    return __int_as_float(__builtin_amdgcn_update_dpp(
        0, __float_as_int(x), CTRL, 0xF, 0xF, true));
}

__global__ __launch_bounds__(64)
void ctc_prob_kernel(const int* __restrict__ y_true,
                     const float* __restrict__ y_pred,
                     float* __restrict__ out) {
    const int b = blockIdx.x;
    const int i = threadIdx.x;
    const bool lane0 = (i == 0);

    const int* lab = y_true + b * Ln;
    const int li   = lab[i];
    const int prev = lab[(i == 0) ? 0 : (i - 1)];
    const bool skip = (i == 0) || (li != prev);

    const float* base = y_pred + (size_t)b * (Tn * Cn);
    const float* pl = base + li;      // this lane's label column
    const float* pb = base + BLANK;   // blank column (wave-uniform)

    float rlA[U], rbA[U], rlB[U], rbB[U], ql[U], qb[U];
    float A0 = 0.0f, Aod = 0.0f, Aev = 0.0f;
    int Esum = 0;

    auto issue = [&](int g, float* rl, float* rb) {
        const float* l  = pl + (size_t)g * (U * Cn);
        const float* bl = pb + (size_t)g * (U * Cn);
#pragma unroll
        for (int j = 0; j < U; ++j) { rl[j] = l[j * Cn]; rb[j] = bl[j * Cn]; }
    };
    auto convert = [&](const float* rl, const float* rb) {
#pragma unroll
        for (int j = 0; j < U; ++j) {
            ql[j] = fmaf(rl[j], 128.0f, EPS128);
            qb[j] = fmaf(rb[j], 128.0f, EPS128);
        }
    };
    auto steps = [&](bool first) {
#pragma unroll
        for (int j = 0; j < U; ++j) {
            if (first && j == 0) {   // t=0: only states 0 and 1 reachable
                A0  = qb[0];
                Aod = lane0 ? ql[0] : 0.0f;
                Aev = 0.0f;
                continue;
            }
            const float odL = dpp_mov<0x138>(Aod);          // alpha[2i-1] (lane0 -> 0)
            const float evS = dpp_mov<0x138>(Aev);
            const float evL = lane0 ? A0 : evS;             // alpha[2i]
            const float sk  = skip ? odL : 0.0f;
            const float nev = (Aev + Aod) * qb[j];          // state 2i+2
            const float nod = (Aod + evL + sk) * ql[j];     // state 2i+1
            A0 *= qb[j];                                    // state 0
            Aod = nod;
            Aev = nev;
        }
    };
    auto renorm = [&]() {
        float m = fmaxf(A0, fmaxf(Aod, Aev));
        m = fmaxf(m, dpp_mov<0x111>(m));   // row_shr:1
        m = fmaxf(m, dpp_mov<0x112>(m));   // row_shr:2
        m = fmaxf(m, dpp_mov<0x114>(m));   // row_shr:4
        m = fmaxf(m, dpp_mov<0x118>(m));   // row_shr:8
        m = fmaxf(m, dpp_mov<0x142>(m));   // row_bcast:15
        m = fmaxf(m, dpp_mov<0x143>(m));   // row_bcast:31 -> lane63 has wave max
        const unsigned ub = (unsigned)__builtin_amdgcn_readlane(__float_as_int(m), 63);
        const int ebits = (int)(ub >> 23);
        const float sc = __int_as_float((254 - ebits) << 23);  // 2^-(e)
        Esum += ebits - 127;
        A0 *= sc; Aod *= sc; Aev *= sc;
    };

    // prologue: groups 0..2 in flight, run group 0
    issue(0, rlA, rbA);
    issue(1, rlB, rbB);
    convert(rlA, rbA);
    issue(2, rlA, rbA);
    steps(true);
    renorm();

    // pairs (1,2), (3,4), ..., (29,30): odd groups live in rB, even in rA
    for (int g = 1; g < NG - 1; g += 2) {
        convert(rlB, rbB);
        if (g + 2 < NG) issue(g + 2, rlB, rbB);
        steps(false);
        renorm();
        convert(rlA, rbA);
        if (g + 3 < NG) issue(g + 3, rlA, rbA);
        steps(false);
        renorm();
    }

    // epilogue: group 31 (odd -> rB)
    convert(rlB, rbB);
    steps(false);

    if (i == 63) {
        // alpha[127] = Aod, alpha[128] = Aev (scaled); unscale via Esum - 7*T
        const float s  = Aod + Aev;
#if __has_builtin(__builtin_amdgcn_logf)
        const float l2 = __builtin_amdgcn_logf(s) + (float)(Esum - 7 * Tn);
#else
        const float l2 = log2f(s) + (float)(Esum - 7 * Tn);
#endif
        out[b] = -l2 * LN2;
    }
}

extern "C" void kernel_launch(void* const* d_in, const int* in_sizes, int n_in,
                              void* d_out, int out_size, void* d_ws, size_t ws_size,
                              hipStream_t stream) {
    const int*   y_true = (const int*)d_in[0];
    const float* y_pred = (const float*)d_in[1];
    float*       out    = (float*)d_out;
    hipLaunchKernelGGL(ctc_prob_kernel, dim3(Bn), dim3(64), 0, stream,
                       y_true, y_pred, out);
}